// Round 18
// baseline (262.201 us; speedup 1.0000x reference)
//
#include <hip/hip_runtime.h>

#define DEVINL __device__ __forceinline__

typedef unsigned short ushort_t;
typedef unsigned long long u64;
typedef __attribute__((ext_vector_type(8))) short short8;
typedef __attribute__((ext_vector_type(8))) unsigned short ushort8;
typedef __attribute__((ext_vector_type(4))) float f32x4;

constexpr int B_ = 8, N_ = 1024, D_ = 64, H_ = 4, QV_ = 32;
constexpr int C_ = 129, K_ = 16, M_ = 4096;
constexpr int NG = B_ * N_;          // 8192 nodes
constexpr int CBS = 160;             // cb logical row width (5 k-tiles; k=129 bias-1.0)
constexpr int VTN = 144;             // vT padded n-dim (9 MFMA n-tiles)
constexpr int KT = 4256;             // hyper GEMM K (133 tiles of 32)
constexpr int NKT = 133;
constexpr int HPS = 544;             // hpb logical row width (17 k-tiles)
constexpr int NCH = NG / 32;         // 256 node-chunks per head (vT tile-major)

// ---- workspace layout (float offsets) ----
constexpr size_t o_cb    = 0;                                   // [5][NG][32] ushort
constexpr size_t o_qb    = o_cb  + (size_t)NG * CBS / 2;        // H*NG*16 ushort
constexpr size_t o_kb    = o_qb  + (size_t)H_ * NG * 16 / 2;    // H*NG*16 ushort
constexpr size_t o_adjb  = o_kb  + (size_t)H_ * NG * 16 / 2;    // 1024*16 u64
constexpr size_t o_wqk   = o_adjb + 32768;                      // [H][5][32][32] ushort
constexpr size_t o_wvt   = o_wqk + (size_t)H_ * 32 * CBS / 2;   // [H][5][144][32] ushort
constexpr size_t o_vT    = o_wvt + (size_t)H_ * VTN * CBS / 2;  // [H][NCH][144][32] ushort
constexpr size_t o_hpb   = o_vT  + (size_t)H_ * VTN * NG / 2;   // [17][M][32] ushort
constexpr size_t o_W1T   = o_hpb + (size_t)M_ * HPS / 2;        // [17][144][32] ushort
constexpr size_t o_W2T   = o_W1T + (size_t)144 * HPS / 2;       // [5][144][32] ushort
constexpr size_t o_wtru  = o_W2T + (size_t)144 * 160 / 2;       // [NKT][128][32] ushort
constexpr size_t o_wtc   = o_wtru + (size_t)128 * KT / 2;       // [NKT][64][32] ushort
constexpr size_t o_A     = o_wtc + (size_t)64 * KT / 2;         // [NKT][M][32] ushort
constexpr size_t o_pru   = o_A + (size_t)M_ * KT / 2;           // 4*M*128 fp32
constexpr size_t o_pc2   = o_pru + (size_t)4 * M_ * 128;        // 4*M*64 fp32

// fused-prep segment bounds (all multiples of 64 -> wave-uniform branches)
constexpr int SEG0 = NG * CBS;                  // cb
constexpr int SEG1 = SEG0 + H_ * 32 * CBS;      // wqk
constexpr int SEG2 = SEG1 + H_ * VTN * CBS;     // wvt
constexpr int SEG3 = SEG2 + 144 * HPS;          // W1T
constexpr int SEG4 = SEG3 + 144 * 160;          // W2T
constexpr int SEG5 = SEG4 + 192 * KT;           // wtru+wtc (tile-major)
constexpr int SEG6 = SEG5 + 1024 * 16 * 64;     // adjb ballot slots

DEVINL float4 ld4(const float* p) { return *reinterpret_cast<const float4*>(p); }
DEVINL void st4(float* p, float4 v) { *reinterpret_cast<float4*>(p) = v; }
DEVINL ushort_t f2bf(float f) {           // RNE fp32->bf16
    unsigned int u = __float_as_uint(f);
    u += 0x7FFFu + ((u >> 16) & 1u);
    return (ushort_t)(u >> 16);
}
DEVINL float bf2f(ushort_t v) { return __uint_as_float((unsigned int)v << 16); }

// ---------------- K0: fused prep — ALL GEMM operands tile-major [kt][row][32] ----------------
__global__ void k_prep(const float* __restrict__ x, const float* __restrict__ h,
                       const float* __restrict__ Wq, const float* __restrict__ bq,
                       const float* __restrict__ Wk, const float* __restrict__ bk,
                       const float* __restrict__ Wv, const float* __restrict__ bv,
                       const float* __restrict__ W1, const float* __restrict__ W2,
                       const float* __restrict__ Wr, const float* __restrict__ br,
                       const float* __restrict__ Wu, const float* __restrict__ bu,
                       const float* __restrict__ Wc, const float* __restrict__ bc,
                       const int* __restrict__ adj,
                       ushort_t* __restrict__ cb, ushort_t* __restrict__ wqk,
                       ushort_t* __restrict__ wvt, ushort_t* __restrict__ W1T,
                       ushort_t* __restrict__ W2T, ushort_t* __restrict__ wtru,
                       ushort_t* __restrict__ wtc, u64* __restrict__ ab) {
    int idx = blockIdx.x * 256 + threadIdx.x;
    if (idx < SEG0) {
        int g = idx / CBS, kk = idx - g * CBS;
        float v;
        if (kk < 65) v = x[g * 65 + kk];
        else if (kk < 129) v = h[g * 64 + (kk - 65)];
        else if (kk == 129) v = 1.0f;
        else v = 0.f;
        cb[((size_t)(kk >> 5) * NG + g) * 32 + (kk & 31)] = f2bf(v);
    } else if (idx < SEG1) {
        int j = idx - SEG0;
        int hh = j / (32 * CBS); int rem = j - hh * 32 * CBS;
        int o = rem / CBS, kk = rem - o * CBS;
        float v = 0.f;
        if (o < 16) {
            if (kk < 129) v = Wq[(size_t)(hh * C_ + kk) * K_ + o];
            else if (kk == 129) v = bq[hh * K_ + o];
        } else {
            int o2 = o - 16;
            if (kk < 129) v = Wk[(size_t)(hh * C_ + kk) * K_ + o2];
            else if (kk == 129) v = bk[hh * K_ + o2];
        }
        wqk[((size_t)(hh * 5 + (kk >> 5)) * 32 + o) * 32 + (kk & 31)] = f2bf(v);
    } else if (idx < SEG2) {
        int j = idx - SEG1;
        int hh = j / (VTN * CBS); int rem = j - hh * VTN * CBS;
        int n = rem / CBS, kk = rem - n * CBS;
        float v = 0.f;
        if (n < C_) {
            if (kk < 129) v = Wv[(size_t)(hh * C_ + kk) * C_ + n];
            else if (kk == 129) v = bv[hh * C_ + n];
        }
        wvt[((size_t)(hh * 5 + (kk >> 5)) * 144 + n) * 32 + (kk & 31)] = f2bf(v);
    } else if (idx < SEG3) {
        int j = idx - SEG2;
        int o = j / HPS, k = j - o * HPS;
        float v = (o < C_ && k < 516) ? W1[(size_t)k * C_ + o] : 0.f;
        W1T[((size_t)(k >> 5) * 144 + o) * 32 + (k & 31)] = f2bf(v);
    } else if (idx < SEG4) {
        int j = idx - SEG3;
        int o = j / 160, k = j - o * 160;
        float v = (o < C_ && k < C_) ? W2[(size_t)k * C_ + o] : 0.f;
        W2T[((size_t)(k >> 5) * 144 + o) * 32 + (k & 31)] = f2bf(v);
    } else if (idx < SEG5) {
        int j = idx - SEG4;
        int row = j / KT, k = j - row * KT;
        float v;
        if (k >= 4224) {
            int d = k - 4224;
            if (row < 64) v = br[d * 64 + row];
            else if (row < 128) v = bu[d * 64 + row - 64];
            else v = bc[d * 64 + row - 128];
        } else {
            int d = k / 132, i = k - d * 132;
            if (i >= 129) v = 0.f;
            else if (row < 64) v = Wr[(size_t)(d * 129 + i) * 64 + row];
            else if (row < 128) v = Wu[(size_t)(d * 129 + i) * 64 + row - 64];
            else v = Wc[(size_t)(d * 129 + i) * 64 + row - 128];
        }
        int kt = k >> 5, kj = k & 31;
        if (row < 128) wtru[((size_t)kt * 128 + row) * 32 + kj] = f2bf(v);
        else wtc[((size_t)kt * 64 + (row - 128)) * 32 + kj] = f2bf(v);
    } else if (idx < SEG6) {
        int j = idx - SEG5;
        int word = j >> 6, lane = j & 63;
        int row = word >> 4, wj = word & 15;
        u64 m = __ballot(adj[(size_t)row * N_ + wj * 64 + lane] != 0);
        if (lane == 0) ab[word] = m;
    }
}

// ---------------- K1: MFMA projections (tile-major); vT written tile-major ----------------
__global__ __launch_bounds__(256) void k_qkv(
    const ushort_t* __restrict__ cb, const ushort_t* __restrict__ wqk,
    const ushort_t* __restrict__ wvt,
    ushort_t* __restrict__ qbo, ushort_t* __restrict__ kbo, ushort_t* __restrict__ vTg) {
    const int t = threadIdx.x;
    const int g0 = blockIdx.x * 16;
    const int hh = blockIdx.y;
    const int lane = t & 63, w = t >> 6;
    const int am = lane & 15, aq = lane >> 4;
    short8 cbf[5];
#pragma unroll
    for (int kt = 0; kt < 5; ++kt)
        cbf[kt] = *reinterpret_cast<const short8*>(&cb[((size_t)kt * NG + g0 + am) * 32 + aq * 8]);
#pragma unroll
    for (int s = 0; s < 3; ++s) {
        int u = w + 4 * s;
        if (u >= 11) break;
        f32x4 acc = f32x4{0.f, 0.f, 0.f, 0.f};
        if (u < 2) {
#pragma unroll
            for (int kt = 0; kt < 5; ++kt) {
                short8 bf = *reinterpret_cast<const short8*>(
                    &wqk[((size_t)(hh * 5 + kt) * 32 + u * 16 + am) * 32 + aq * 8]);
                acc = __builtin_amdgcn_mfma_f32_16x16x32_bf16(cbf[kt], bf, acc, 0, 0, 0);
            }
            ushort_t* dst = u ? kbo : qbo;
#pragma unroll
            for (int i = 0; i < 4; ++i)
                dst[(size_t)(hh * NG + g0 + aq * 4 + i) * 16 + am] = f2bf(acc[i]);
        } else {
            int vt = u - 2;
#pragma unroll
            for (int kt = 0; kt < 5; ++kt) {
                short8 af = *reinterpret_cast<const short8*>(
                    &wvt[((size_t)(hh * 5 + kt) * 144 + vt * 16 + am) * 32 + aq * 8]);
                acc = __builtin_amdgcn_mfma_f32_16x16x32_bf16(af, cbf[kt], acc, 0, 0, 0);
            }
            // C-layout: row (aq*4+i) = feature (A's M dim), col (am) = node (B's N dim)
            const int g = g0 + am;                 // node; g>>5 constant within block
#pragma unroll
            for (int i = 0; i < 4; ++i) {
                int feat = vt * 16 + aq * 4 + i;
                vTg[(((size_t)hh * NCH + (g >> 5)) * 144 + feat) * 32 + (g & 31)] = f2bf(acc[i]);
            }
        }
    }
}

// ---------------- K3: attention (XCD swizzle, tile-major vT, bf16 Ored partials) ----------------
__global__ __launch_bounds__(256) void k_attn(
    const ushort_t* __restrict__ qb, const ushort_t* __restrict__ kb,
    const ushort_t* __restrict__ vTg, const u64* __restrict__ adjb,
    const int* __restrict__ nodes_b, const int* __restrict__ nodes_n,
    ushort_t* __restrict__ hpb) {
    __shared__ u64 Msk[16][16];
    __shared__ alignas(16) ushort_t Pb[4][16 * 72];
    __shared__ ushort_t Oredb[3][16 * 144];       // bf16 partials (halves LDS vs fp32)
    __shared__ float Lpart[4][16];
    __shared__ float Linv[16];
    __shared__ int Nrow[16];
    const int t = threadIdx.x;
    const int bi = blockIdx.x;
    const int mx = ((bi & 7) << 5) + (bi >> 3);   // XCD i <- batch i
    const int m0 = mx * 16;
    const int hh = blockIdx.y;
    const int b = nodes_b[m0];
    if (t < 16) Nrow[t] = nodes_n[m0 + t];
    __syncthreads();
    { int r = t >> 4, wj = t & 15; Msk[r][wj] = adjb[Nrow[r] * 16 + wj]; }
    const int lane = t & 63, w = t >> 6;
    const int am = lane & 15, aq = lane >> 4;
    short8 qf = short8{0, 0, 0, 0, 0, 0, 0, 0};
    if (aq < 2)
        qf = *reinterpret_cast<const short8*>(&qb[(size_t)(hh * NG + b * N_ + Nrow[am]) * 16 + aq * 8]);
    __syncthreads();
    ushort_t* Pw = Pb[w];
    const ushort_t* kbase = kb + ((size_t)hh * NG + b * N_) * 16;
    const ushort_t* vbase = vTg + ((size_t)hh * NCH + b * 32) * 144 * 32;
    f32x4 accv[9];
#pragma unroll
    for (int j = 0; j < 9; ++j) accv[j] = f32x4{0.f, 0.f, 0.f, 0.f};
    float lsum[4] = {0.f, 0.f, 0.f, 0.f};

    for (int ti = 0; ti < 4; ++ti) {
        const int tile = w + 4 * ti;
        const int c0 = tile * 64;
        u64 mrow[4];
#pragma unroll
        for (int i = 0; i < 4; ++i) mrow[i] = Msk[aq * 4 + i][tile];
#pragma unroll
        for (int nt = 0; nt < 4; ++nt) {
            int col = c0 + nt * 16 + am;
            short8 bf = short8{0, 0, 0, 0, 0, 0, 0, 0};
            if (aq < 2)
                bf = *reinterpret_cast<const short8*>(&kbase[(size_t)col * 16 + aq * 8]);
            f32x4 sv = __builtin_amdgcn_mfma_f32_16x16x32_bf16(qf, bf, f32x4{0.f, 0.f, 0.f, 0.f}, 0, 0, 0);
#pragma unroll
            for (int i = 0; i < 4; ++i) {
                float s = sv[i] * 0.25f;
                s = (s >= 0.f) ? s : 0.2f * s;
                float p = ((mrow[i] >> (nt * 16 + am)) & 1ull) ? __expf(s) : 0.f;
                lsum[i] += p;
                Pw[(aq * 4 + i) * 72 + nt * 16 + am] = f2bf(p);
            }
        }
#pragma unroll
        for (int kh = 0; kh < 2; ++kh) {
            short8 af = *reinterpret_cast<const short8*>(&Pw[am * 72 + kh * 32 + aq * 8]);
            const ushort_t* vch = vbase + ((size_t)((c0 >> 5) + kh) * 144) * 32;
#pragma unroll
            for (int nt = 0; nt < 9; ++nt) {
                short8 bfr = *reinterpret_cast<const short8*>(
                    &vch[(size_t)(nt * 16 + am) * 32 + aq * 8]);
                accv[nt] = __builtin_amdgcn_mfma_f32_16x16x32_bf16(af, bfr, accv[nt], 0, 0, 0);
            }
        }
    }
#pragma unroll
    for (int i = 0; i < 4; ++i) {
        float v = lsum[i];
        v += __shfl_xor(v, 1); v += __shfl_xor(v, 2);
        v += __shfl_xor(v, 4); v += __shfl_xor(v, 8);
        if (am == 0) Lpart[w][aq * 4 + i] = v;
    }
    if (w > 0) {
#pragma unroll
        for (int nt = 0; nt < 9; ++nt)
#pragma unroll
            for (int i = 0; i < 4; ++i)
                Oredb[w - 1][(aq * 4 + i) * 144 + nt * 16 + am] = f2bf(accv[nt][i]);
    }
    __syncthreads();
    if (w == 0) {
        if (t < 16) {
            float s = Lpart[0][t] + Lpart[1][t] + Lpart[2][t] + Lpart[3][t];
            Linv[t] = (s > 0.f) ? 1.f / s : 0.f;
        }
#pragma unroll
        for (int nt = 0; nt < 9; ++nt) {
            int col = nt * 16 + am;
            if (col < C_) {
                int k = hh * C_ + col;
#pragma unroll
                for (int i = 0; i < 4; ++i) {
                    int row = aq * 4 + i;
                    float val = accv[nt][i] + bf2f(Oredb[0][row * 144 + col])
                              + bf2f(Oredb[1][row * 144 + col]) + bf2f(Oredb[2][row * 144 + col]);
                    hpb[((size_t)(k >> 5) * M_ + m0 + row) * 32 + (k & 31)] = f2bf(val * Linv[row]);
                }
            }
        }
    }
    if (hh == 3) {   // zero pad k = 516..543
        for (int idx = t; idx < 16 * 28; idx += 256) {
            int rr = idx / 28, cc = 516 + (idx - rr * 28);
            hpb[((size_t)(cc >> 5) * M_ + m0 + rr) * 32 + (cc & 31)] = 0;
        }
    }
}

// ---------------- K4: node MLP + skip, fused A-build (selx never materialized) ----------------
__global__ __launch_bounds__(256) void k_mlp(
    const ushort_t* __restrict__ hpb,
    const ushort_t* __restrict__ W1T, const float* __restrict__ b1,
    const ushort_t* __restrict__ W2T, const float* __restrict__ b2,
    const float* __restrict__ x, const float* __restrict__ h,
    const int* __restrict__ nb, const int* __restrict__ nn,
    const float* __restrict__ qv, ushort_t* __restrict__ A) {
    __shared__ alignas(16) ushort_t Hs[16 * 168];
    __shared__ float Sx[16][136];                 // selx rows fp32
    __shared__ float Qs[16][32];
    const int t = threadIdx.x;
    const int m0 = blockIdx.x * 16;
    const int lane = t & 63, w = t >> 6;
    const int am = lane & 15, aq = lane >> 4;
    // stage qv for this block's 16 rows
    for (int idx = t; idx < 512; idx += 256) {
        int r = idx >> 5, d = idx & 31;
        Qs[r][d] = qv[(size_t)(m0 + r) * QV_ + d];
    }
    f32x4 acc[3];
#pragma unroll
    for (int j = 0; j < 3; ++j) acc[j] = f32x4{0.f, 0.f, 0.f, 0.f};
    for (int kt = 0; kt < 17; ++kt) {
        short8 af = *reinterpret_cast<const short8*>(&hpb[((size_t)kt * M_ + m0 + am) * 32 + aq * 8]);
#pragma unroll
        for (int j = 0; j < 3; ++j) {
            int nt = w + 4 * j;
            if (nt < 9) {
                short8 bf = *reinterpret_cast<const short8*>(
                    &W1T[((size_t)kt * 144 + nt * 16 + am) * 32 + aq * 8]);
                acc[j] = __builtin_amdgcn_mfma_f32_16x16x32_bf16(af, bf, acc[j], 0, 0, 0);
            }
        }
    }
#pragma unroll
    for (int j = 0; j < 3; ++j) {
        int nt = w + 4 * j;
        if (nt < 9) {
            int col = nt * 16 + am;
            float bb = (col < C_) ? b1[col] : 0.f;
#pragma unroll
            for (int i = 0; i < 4; ++i) {
                int row = aq * 4 + i;
                float v = (col < C_) ? fmaxf(acc[j][i] + bb, 0.f) : 0.f;
                Hs[row * 168 + col] = f2bf(v);
            }
        }
    }
    { int row = t >> 4, cc = 144 + (t & 15); Hs[row * 168 + cc] = 0; }
    __syncthreads();
    f32x4 acc2[3];
#pragma unroll
    for (int j = 0; j < 3; ++j) acc2[j] = f32x4{0.f, 0.f, 0.f, 0.f};
    for (int kt = 0; kt < 5; ++kt) {
        short8 af = *reinterpret_cast<const short8*>(&Hs[am * 168 + kt * 32 + aq * 8]);
#pragma unroll
        for (int j = 0; j < 3; ++j) {
            int nt = w + 4 * j;
            if (nt < 9) {
                short8 bf = *reinterpret_cast<const short8*>(
                    &W2T[((size_t)kt * 144 + nt * 16 + am) * 32 + aq * 8]);
                acc2[j] = __builtin_amdgcn_mfma_f32_16x16x32_bf16(af, bf, acc2[j], 0, 0, 0);
            }
        }
    }
    // selx rows -> LDS (mlp_out + bias + skip); pad cols 129..131 = 0
#pragma unroll
    for (int j = 0; j < 3; ++j) {
        int nt = w + 4 * j;
        if (nt < 9) {
            int col = nt * 16 + am;
            if (col < C_) {
                float bb = b2[col];
#pragma unroll
                for (int i = 0; i < 4; ++i) {
                    int row = aq * 4 + i;
                    int m = m0 + row;
                    int b = nb[m], n = nn[m];
                    float sk = (col < 65) ? x[(b * N_ + n) * 65 + col]
                                          : h[(b * N_ + n) * D_ + (col - 65)];
                    Sx[row][col] = acc2[j][i] + bb + sk;
                }
            }
        }
    }
    if (t < 48) { int rr = t / 3, cc = 129 + (t - (t / 3) * 3); Sx[rr][cc] = 0.f; }
    __syncthreads();
    // tile-major A write: A[kt][m][32] = qv[m][d] * selx[m][i],  k = d*132+i; bias slots at kt=132
    for (int r = 0; r < 16; ++r) {
        const int m = m0 + r;
        for (int k = t; k < 4224; k += 256) {
            int d = k / 132, i = k - d * 132;
            A[((size_t)(k >> 5) * M_ + m) * 32 + (k & 31)] = f2bf(Qs[r][d] * Sx[r][i]);
        }
        if (t < QV_) A[((size_t)132 * M_ + m) * 32 + t] = f2bf(Qs[r][t]);
    }
}

// ---------------- K5a2: build A for cand pass — sel row built inline from x,h,pru ----------------
__global__ __launch_bounds__(256) void k_arow2(const float* __restrict__ x,
                                               const float* __restrict__ h,
                                               const int* __restrict__ nb,
                                               const int* __restrict__ nn,
                                               const float* __restrict__ pru,
                                               const float* __restrict__ qv,
                                               ushort_t* __restrict__ A) {
    __shared__ float sq[132];
    __shared__ float qs[QV_];
    const int t = threadIdx.x;
    const int m = blockIdx.x;
    const int b = nb[m], n = nn[m];
    if (t < 65) sq[t] = x[(b * N_ + n) * 65 + t];
    else if (t < 129) {
        int o = t - 65;
        const size_t S = (size_t)M_ * 128;
        size_t base = (size_t)m * 128 + o;
        float s = pru[base] + pru[S + base] + pru[2 * S + base] + pru[3 * S + base];
        float rv = 1.f / (1.f + __expf(-s));
        sq[t] = rv * h[(b * N_ + n) * D_ + o];
    } else if (t < 132) sq[t] = 0.f;
    if (t >= 224) qs[t - 224] = qv[m * QV_ + (t - 224)];
    __syncthreads();
    for (int k = t; k < 4224; k += 256) {
        int d = k / 132, i = k - d * 132;
        A[((size_t)(k >> 5) * M_ + m) * 32 + (k & 31)] = f2bf(qs[d] * sq[i]);
    }
    if (t < QV_) A[((size_t)132 * M_ + m) * 32 + t] = f2bf(qs[t]);
}

// ---------------- K5b: hyper GEMM, tile-major operands, 32-row m-tiles ----------------
template<int NN>
__global__ __launch_bounds__(256) void k_gemm(const ushort_t* __restrict__ A,
                                              const ushort_t* __restrict__ WT,
                                              float* __restrict__ part) {
    const int t = threadIdx.x;
    const int m0 = blockIdx.x * 32;
    const int z = blockIdx.y;
    const int lane = t & 63, w = t >> 6;
    const int am = lane & 15, aq = lane >> 4;
    constexpr int NTpW = NN / 64;
    const int ktb = z * 34;
    const int kte = (ktb + 34 < NKT) ? ktb + 34 : NKT;
    f32x4 acc[2][NTpW];
#pragma unroll
    for (int r2 = 0; r2 < 2; ++r2)
#pragma unroll
        for (int j = 0; j < NTpW; ++j) acc[r2][j] = f32x4{0.f, 0.f, 0.f, 0.f};
    for (int kt = ktb; kt < kte; ++kt) {
        const ushort_t* Ab = A + ((size_t)kt * M_ + m0) * 32 + aq * 8;
        short8 a0 = *reinterpret_cast<const short8*>(Ab + am * 32);
        short8 a1 = *reinterpret_cast<const short8*>(Ab + (am + 16) * 32);
        const ushort_t* Bb = WT + (size_t)kt * NN * 32 + am * 32 + aq * 8;
#pragma unroll
        for (int j = 0; j < NTpW; ++j) {
            int nt = w + 4 * j;
            short8 bf = *reinterpret_cast<const short8*>(Bb + nt * 16 * 32);
            acc[0][j] = __builtin_amdgcn_mfma_f32_16x16x32_bf16(a0, bf, acc[0][j], 0, 0, 0);
            acc[1][j] = __builtin_amdgcn_mfma_f32_16x16x32_bf16(a1, bf, acc[1][j], 0, 0, 0);
        }
    }
#pragma unroll
    for (int j = 0; j < NTpW; ++j) {
        int n = (w + 4 * j) * 16 + am;
#pragma unroll
        for (int r2 = 0; r2 < 2; ++r2)
#pragma unroll
            for (int i = 0; i < 4; ++i) {
                int m = m0 + r2 * 16 + aq * 4 + i;
                part[((size_t)z * M_ + m) * NN + n] = acc[r2][j][i];
            }
    }
}

// ---------------- K5d: final gate (r-gate recomputed inline) ----------------
__global__ void k_final(const float* __restrict__ pru, const float* __restrict__ pc,
                        const float* __restrict__ h,
                        const int* __restrict__ nb, const int* __restrict__ nn,
                        float* __restrict__ out) {
    int idx = blockIdx.x * 256 + threadIdx.x;
    if (idx >= M_ * D_) return;
    int m = idx >> 6, o = idx & 63;
    const size_t Su = (size_t)M_ * 128;
    size_t br_ = (size_t)m * 128 + o;
    size_t bu = br_ + 64;
    float sr = pru[br_] + pru[Su + br_] + pru[2 * Su + br_] + pru[3 * Su + br_];
    float rv = 1.f / (1.f + __expf(-sr));
    float su = pru[bu] + pru[Su + bu] + pru[2 * Su + bu] + pru[3 * Su + bu];
    float uv = 1.f / (1.f + __expf(-su));
    const size_t Sc = (size_t)M_ * 64;
    size_t bcx = (size_t)m * 64 + o;
    float sc = pc[bcx] + pc[Sc + bcx] + pc[2 * Sc + bcx] + pc[3 * Sc + bcx];
    float cand = tanhf(sc);
    int b = nb[m], n = nn[m];
    float hn = rv * h[(b * N_ + n) * D_ + o];
    out[idx] = (1.f - uv) * hn + uv * cand;
}

extern "C" void kernel_launch(void* const* d_in, const int* in_sizes, int n_in,
                              void* d_out, int out_size, void* d_ws, size_t ws_size,
                              hipStream_t stream) {
    const float* x   = (const float*)d_in[0];
    const float* h   = (const float*)d_in[1];
    const float* qv  = (const float*)d_in[2];
    const int*   adj = (const int*)d_in[3];
    const int*   nb  = (const int*)d_in[4];
    const int*   nn  = (const int*)d_in[5];
    const float* Wq  = (const float*)d_in[6];
    const float* bq  = (const float*)d_in[7];
    const float* Wk  = (const float*)d_in[8];
    const float* bk  = (const float*)d_in[9];
    const float* Wv  = (const float*)d_in[10];
    const float* bv  = (const float*)d_in[11];
    const float* W1  = (const float*)d_in[12];
    const float* b1  = (const float*)d_in[13];
    const float* W2  = (const float*)d_in[14];
    const float* b2  = (const float*)d_in[15];
    const float* Wr  = (const float*)d_in[16];
    const float* br  = (const float*)d_in[17];
    const float* Wu  = (const float*)d_in[18];
    const float* bu  = (const float*)d_in[19];
    const float* Wc  = (const float*)d_in[20];
    const float* bc  = (const float*)d_in[21];
    float* ws = (float*)d_ws;
    float* out = (float*)d_out;

    ushort_t* cb   = (ushort_t*)(ws + o_cb);
    ushort_t* qb   = (ushort_t*)(ws + o_qb);
    ushort_t* kb   = (ushort_t*)(ws + o_kb);
    u64*      ab   = (u64*)(ws + o_adjb);
    ushort_t* wqk  = (ushort_t*)(ws + o_wqk);
    ushort_t* wvt  = (ushort_t*)(ws + o_wvt);
    ushort_t* vTg  = (ushort_t*)(ws + o_vT);
    ushort_t* hpb  = (ushort_t*)(ws + o_hpb);
    ushort_t* W1T  = (ushort_t*)(ws + o_W1T);
    ushort_t* W2T  = (ushort_t*)(ws + o_W2T);
    ushort_t* wtru = (ushort_t*)(ws + o_wtru);
    ushort_t* wtc  = (ushort_t*)(ws + o_wtc);
    ushort_t* Abuf = (ushort_t*)(ws + o_A);
    float* pru   = ws + o_pru;
    float* pc    = ws + o_pc2;

    k_prep<<<(SEG6 + 255) / 256, 256, 0, stream>>>(
        x, h, Wq, bq, Wk, bk, Wv, bv, W1, W2, Wr, br, Wu, bu, Wc, bc, adj,
        cb, wqk, wvt, W1T, W2T, wtru, wtc, ab);
    k_qkv<<<dim3(NG / 16, H_), 256, 0, stream>>>(cb, wqk, wvt, qb, kb, vTg);
    k_attn<<<dim3(M_ / 16, H_), 256, 0, stream>>>(qb, kb, vTg, ab, nb, nn, hpb);
    k_mlp<<<M_ / 16, 256, 0, stream>>>(hpb, W1T, b1, W2T, b2, x, h, nb, nn, qv, Abuf);
    k_gemm<128><<<dim3(M_ / 32, 4), 256, 0, stream>>>(Abuf, wtru, pru);
    k_arow2<<<M_, 256, 0, stream>>>(x, h, nb, nn, pru, qv, Abuf);
    k_gemm<64><<<dim3(M_ / 32, 4), 256, 0, stream>>>(Abuf, wtc, pc);
    k_final<<<(M_ * D_ + 255) / 256, 256, 0, stream>>>(pru, pc, h, nb, nn, out);
}

// Round 19
// 257.951 us; speedup vs baseline: 1.0165x; 1.0165x over previous
//
#include <hip/hip_runtime.h>

#define DEVINL __device__ __forceinline__

typedef unsigned short ushort_t;
typedef unsigned long long u64;
typedef __attribute__((ext_vector_type(8))) short short8;
typedef __attribute__((ext_vector_type(8))) unsigned short ushort8;
typedef __attribute__((ext_vector_type(4))) float f32x4;

constexpr int B_ = 8, N_ = 1024, D_ = 64, H_ = 4, QV_ = 32;
constexpr int C_ = 129, K_ = 16, M_ = 4096;
constexpr int CP = 132;              // cpost fp32 row stride
constexpr int NG = B_ * N_;          // 8192 nodes
constexpr int CBS = 160;             // cb logical row width (5 k-tiles; k=129 bias-1.0)
constexpr int VTN = 144;             // vT padded n-dim (9 MFMA n-tiles)
constexpr int KT = 4256;             // hyper GEMM K (133 tiles of 32)
constexpr int NKT = 133;
constexpr int ZS = 8;                // k-split chunks (17 k-tiles each)
constexpr int HPS = 544;             // hpb logical row width (17 k-tiles)
constexpr int NCH = NG / 32;         // 256 node-chunks per head (vT tile-major)

// ---- workspace layout (float offsets) ----
constexpr size_t o_cb    = 0;                                   // [5][NG][32] ushort
constexpr size_t o_qb    = o_cb  + (size_t)NG * CBS / 2;        // H*NG*16 ushort
constexpr size_t o_kb    = o_qb  + (size_t)H_ * NG * 16 / 2;    // H*NG*16 ushort
constexpr size_t o_adjb  = o_kb  + (size_t)H_ * NG * 16 / 2;    // 1024*16 u64
constexpr size_t o_wqk   = o_adjb + 32768;                      // [H][5][32][32] ushort
constexpr size_t o_wvt   = o_wqk + (size_t)H_ * 32 * CBS / 2;   // [H][5][144][32] ushort
constexpr size_t o_vT    = o_wvt + (size_t)H_ * VTN * CBS / 2;  // [H][NCH][144][32] ushort
constexpr size_t o_hpb   = o_vT  + (size_t)H_ * VTN * NG / 2;   // [17][M][32] ushort
constexpr size_t o_cpost = o_hpb + (size_t)M_ * HPS / 2;        // M*CP fp32
constexpr size_t o_W1T   = o_cpost + (size_t)M_ * CP;           // [17][144][32] ushort
constexpr size_t o_W2T   = o_W1T + (size_t)144 * HPS / 2;       // [5][144][32] ushort
constexpr size_t o_wtru  = o_W2T + (size_t)144 * 160 / 2;       // [NKT][128][32] ushort
constexpr size_t o_wtc   = o_wtru + (size_t)128 * KT / 2;       // [NKT][64][32] ushort
constexpr size_t o_A     = o_wtc + (size_t)64 * KT / 2;         // [NKT][M][32] ushort
constexpr size_t o_pru   = o_A + (size_t)M_ * KT / 2;           // ZS*M*128 fp32
constexpr size_t o_pc2   = o_pru + (size_t)ZS * M_ * 128;       // ZS*M*64 fp32

// fused-prep segment bounds (all multiples of 64 -> wave-uniform branches)
constexpr int SEG0 = NG * CBS;                  // cb
constexpr int SEG1 = SEG0 + H_ * 32 * CBS;      // wqk
constexpr int SEG2 = SEG1 + H_ * VTN * CBS;     // wvt
constexpr int SEG3 = SEG2 + 144 * HPS;          // W1T
constexpr int SEG4 = SEG3 + 144 * 160;          // W2T
constexpr int SEG5 = SEG4 + 192 * KT;           // wtru+wtc (tile-major)
constexpr int SEG6 = SEG5 + 1024 * 16 * 64;     // adjb ballot slots

DEVINL float4 ld4(const float* p) { return *reinterpret_cast<const float4*>(p); }
DEVINL void st4(float* p, float4 v) { *reinterpret_cast<float4*>(p) = v; }
DEVINL ushort_t f2bf(float f) {           // RNE fp32->bf16
    unsigned int u = __float_as_uint(f);
    u += 0x7FFFu + ((u >> 16) & 1u);
    return (ushort_t)(u >> 16);
}

// ---------------- K0: fused prep — ALL GEMM operands tile-major [kt][row][32] ----------------
__global__ void k_prep(const float* __restrict__ x, const float* __restrict__ h,
                       const float* __restrict__ Wq, const float* __restrict__ bq,
                       const float* __restrict__ Wk, const float* __restrict__ bk,
                       const float* __restrict__ Wv, const float* __restrict__ bv,
                       const float* __restrict__ W1, const float* __restrict__ W2,
                       const float* __restrict__ Wr, const float* __restrict__ br,
                       const float* __restrict__ Wu, const float* __restrict__ bu,
                       const float* __restrict__ Wc, const float* __restrict__ bc,
                       const int* __restrict__ adj,
                       ushort_t* __restrict__ cb, ushort_t* __restrict__ wqk,
                       ushort_t* __restrict__ wvt, ushort_t* __restrict__ W1T,
                       ushort_t* __restrict__ W2T, ushort_t* __restrict__ wtru,
                       ushort_t* __restrict__ wtc, u64* __restrict__ ab) {
    int idx = blockIdx.x * 256 + threadIdx.x;
    if (idx < SEG0) {
        int g = idx / CBS, kk = idx - g * CBS;
        float v;
        if (kk < 65) v = x[g * 65 + kk];
        else if (kk < 129) v = h[g * 64 + (kk - 65)];
        else if (kk == 129) v = 1.0f;
        else v = 0.f;
        cb[((size_t)(kk >> 5) * NG + g) * 32 + (kk & 31)] = f2bf(v);
    } else if (idx < SEG1) {
        int j = idx - SEG0;
        int hh = j / (32 * CBS); int rem = j - hh * 32 * CBS;
        int o = rem / CBS, kk = rem - o * CBS;
        float v = 0.f;
        if (o < 16) {
            if (kk < 129) v = Wq[(size_t)(hh * C_ + kk) * K_ + o];
            else if (kk == 129) v = bq[hh * K_ + o];
        } else {
            int o2 = o - 16;
            if (kk < 129) v = Wk[(size_t)(hh * C_ + kk) * K_ + o2];
            else if (kk == 129) v = bk[hh * K_ + o2];
        }
        wqk[((size_t)(hh * 5 + (kk >> 5)) * 32 + o) * 32 + (kk & 31)] = f2bf(v);
    } else if (idx < SEG2) {
        int j = idx - SEG1;
        int hh = j / (VTN * CBS); int rem = j - hh * VTN * CBS;
        int n = rem / CBS, kk = rem - n * CBS;
        float v = 0.f;
        if (n < C_) {
            if (kk < 129) v = Wv[(size_t)(hh * C_ + kk) * C_ + n];
            else if (kk == 129) v = bv[hh * C_ + n];
        }
        wvt[((size_t)(hh * 5 + (kk >> 5)) * 144 + n) * 32 + (kk & 31)] = f2bf(v);
    } else if (idx < SEG3) {
        int j = idx - SEG2;
        int o = j / HPS, k = j - o * HPS;
        float v = (o < C_ && k < 516) ? W1[(size_t)k * C_ + o] : 0.f;
        W1T[((size_t)(k >> 5) * 144 + o) * 32 + (k & 31)] = f2bf(v);
    } else if (idx < SEG4) {
        int j = idx - SEG3;
        int o = j / 160, k = j - o * 160;
        float v = (o < C_ && k < C_) ? W2[(size_t)k * C_ + o] : 0.f;
        W2T[((size_t)(k >> 5) * 144 + o) * 32 + (k & 31)] = f2bf(v);
    } else if (idx < SEG5) {
        int j = idx - SEG4;
        int row = j / KT, k = j - row * KT;
        float v;
        if (k >= 4224) {
            int d = k - 4224;
            if (row < 64) v = br[d * 64 + row];
            else if (row < 128) v = bu[d * 64 + row - 64];
            else v = bc[d * 64 + row - 128];
        } else {
            int d = k / 132, i = k - d * 132;
            if (i >= 129) v = 0.f;
            else if (row < 64) v = Wr[(size_t)(d * 129 + i) * 64 + row];
            else if (row < 128) v = Wu[(size_t)(d * 129 + i) * 64 + row - 64];
            else v = Wc[(size_t)(d * 129 + i) * 64 + row - 128];
        }
        int kt = k >> 5, kj = k & 31;
        if (row < 128) wtru[((size_t)kt * 128 + row) * 32 + kj] = f2bf(v);
        else wtc[((size_t)kt * 64 + (row - 128)) * 32 + kj] = f2bf(v);
    } else if (idx < SEG6) {
        int j = idx - SEG5;
        int word = j >> 6, lane = j & 63;
        int row = word >> 4, wj = word & 15;
        u64 m = __ballot(adj[(size_t)row * N_ + wj * 64 + lane] != 0);
        if (lane == 0) ab[word] = m;
    }
}

// ---------------- K1: MFMA projections (tile-major); vT written tile-major ----------------
__global__ __launch_bounds__(256) void k_qkv(
    const ushort_t* __restrict__ cb, const ushort_t* __restrict__ wqk,
    const ushort_t* __restrict__ wvt,
    ushort_t* __restrict__ qbo, ushort_t* __restrict__ kbo, ushort_t* __restrict__ vTg) {
    const int t = threadIdx.x;
    const int g0 = blockIdx.x * 16;
    const int hh = blockIdx.y;
    const int lane = t & 63, w = t >> 6;
    const int am = lane & 15, aq = lane >> 4;
    short8 cbf[5];
#pragma unroll
    for (int kt = 0; kt < 5; ++kt)
        cbf[kt] = *reinterpret_cast<const short8*>(&cb[((size_t)kt * NG + g0 + am) * 32 + aq * 8]);
#pragma unroll
    for (int s = 0; s < 3; ++s) {
        int u = w + 4 * s;
        if (u >= 11) break;
        f32x4 acc = f32x4{0.f, 0.f, 0.f, 0.f};
        if (u < 2) {
#pragma unroll
            for (int kt = 0; kt < 5; ++kt) {
                short8 bf = *reinterpret_cast<const short8*>(
                    &wqk[((size_t)(hh * 5 + kt) * 32 + u * 16 + am) * 32 + aq * 8]);
                acc = __builtin_amdgcn_mfma_f32_16x16x32_bf16(cbf[kt], bf, acc, 0, 0, 0);
            }
            ushort_t* dst = u ? kbo : qbo;
#pragma unroll
            for (int i = 0; i < 4; ++i)
                dst[(size_t)(hh * NG + g0 + aq * 4 + i) * 16 + am] = f2bf(acc[i]);
        } else {
            int vt = u - 2;
#pragma unroll
            for (int kt = 0; kt < 5; ++kt) {
                short8 af = *reinterpret_cast<const short8*>(
                    &wvt[((size_t)(hh * 5 + kt) * 144 + vt * 16 + am) * 32 + aq * 8]);
                acc = __builtin_amdgcn_mfma_f32_16x16x32_bf16(af, cbf[kt], acc, 0, 0, 0);
            }
            // C-layout: row (aq*4+i) = feature (A's M dim), col (am) = node (B's N dim)
            const int g = g0 + am;                 // node; g>>5 constant within block
#pragma unroll
            for (int i = 0; i < 4; ++i) {
                int feat = vt * 16 + aq * 4 + i;
                vTg[(((size_t)hh * NCH + (g >> 5)) * 144 + feat) * 32 + (g & 31)] = f2bf(acc[i]);
            }
        }
    }
}

// ---------------- K3: attention (r17 structure: fp32 Ored, XCD swizzle, tile-major vT) ---------
__global__ __launch_bounds__(256) void k_attn(
    const ushort_t* __restrict__ qb, const ushort_t* __restrict__ kb,
    const ushort_t* __restrict__ vTg, const u64* __restrict__ adjb,
    const int* __restrict__ nodes_b, const int* __restrict__ nodes_n,
    ushort_t* __restrict__ hpb) {
    __shared__ u64 Msk[16][16];
    __shared__ alignas(16) ushort_t Pb[4][16 * 72];
    __shared__ float Ored[3][16 * 144];
    __shared__ float Lpart[4][16];
    __shared__ float Linv[16];
    __shared__ int Nrow[16];
    const int t = threadIdx.x;
    const int bi = blockIdx.x;
    const int mx = ((bi & 7) << 5) + (bi >> 3);   // XCD i <- batch i
    const int m0 = mx * 16;
    const int hh = blockIdx.y;
    const int b = nodes_b[m0];
    if (t < 16) Nrow[t] = nodes_n[m0 + t];
    __syncthreads();
    { int r = t >> 4, wj = t & 15; Msk[r][wj] = adjb[Nrow[r] * 16 + wj]; }
    const int lane = t & 63, w = t >> 6;
    const int am = lane & 15, aq = lane >> 4;
    short8 qf = short8{0, 0, 0, 0, 0, 0, 0, 0};
    if (aq < 2)
        qf = *reinterpret_cast<const short8*>(&qb[(size_t)(hh * NG + b * N_ + Nrow[am]) * 16 + aq * 8]);
    __syncthreads();
    ushort_t* Pw = Pb[w];
    const ushort_t* kbase = kb + ((size_t)hh * NG + b * N_) * 16;
    const ushort_t* vbase = vTg + ((size_t)hh * NCH + b * 32) * 144 * 32;
    f32x4 accv[9];
#pragma unroll
    for (int j = 0; j < 9; ++j) accv[j] = f32x4{0.f, 0.f, 0.f, 0.f};
    float lsum[4] = {0.f, 0.f, 0.f, 0.f};

    for (int ti = 0; ti < 4; ++ti) {
        const int tile = w + 4 * ti;
        const int c0 = tile * 64;
        u64 mrow[4];
#pragma unroll
        for (int i = 0; i < 4; ++i) mrow[i] = Msk[aq * 4 + i][tile];
#pragma unroll
        for (int nt = 0; nt < 4; ++nt) {
            int col = c0 + nt * 16 + am;
            short8 bf = short8{0, 0, 0, 0, 0, 0, 0, 0};
            if (aq < 2)
                bf = *reinterpret_cast<const short8*>(&kbase[(size_t)col * 16 + aq * 8]);
            f32x4 sv = __builtin_amdgcn_mfma_f32_16x16x32_bf16(qf, bf, f32x4{0.f, 0.f, 0.f, 0.f}, 0, 0, 0);
#pragma unroll
            for (int i = 0; i < 4; ++i) {
                float s = sv[i] * 0.25f;
                s = (s >= 0.f) ? s : 0.2f * s;
                float p = ((mrow[i] >> (nt * 16 + am)) & 1ull) ? __expf(s) : 0.f;
                lsum[i] += p;
                Pw[(aq * 4 + i) * 72 + nt * 16 + am] = f2bf(p);
            }
        }
#pragma unroll
        for (int kh = 0; kh < 2; ++kh) {
            short8 af = *reinterpret_cast<const short8*>(&Pw[am * 72 + kh * 32 + aq * 8]);
            const ushort_t* vch = vbase + ((size_t)((c0 >> 5) + kh) * 144) * 32;
#pragma unroll
            for (int nt = 0; nt < 9; ++nt) {
                short8 bfr = *reinterpret_cast<const short8*>(
                    &vch[(size_t)(nt * 16 + am) * 32 + aq * 8]);
                accv[nt] = __builtin_amdgcn_mfma_f32_16x16x32_bf16(af, bfr, accv[nt], 0, 0, 0);
            }
        }
    }
#pragma unroll
    for (int i = 0; i < 4; ++i) {
        float v = lsum[i];
        v += __shfl_xor(v, 1); v += __shfl_xor(v, 2);
        v += __shfl_xor(v, 4); v += __shfl_xor(v, 8);
        if (am == 0) Lpart[w][aq * 4 + i] = v;
    }
    if (w > 0) {
#pragma unroll
        for (int nt = 0; nt < 9; ++nt)
#pragma unroll
            for (int i = 0; i < 4; ++i)
                Ored[w - 1][(aq * 4 + i) * 144 + nt * 16 + am] = accv[nt][i];
    }
    __syncthreads();
    if (w == 0) {
        if (t < 16) {
            float s = Lpart[0][t] + Lpart[1][t] + Lpart[2][t] + Lpart[3][t];
            Linv[t] = (s > 0.f) ? 1.f / s : 0.f;
        }
#pragma unroll
        for (int nt = 0; nt < 9; ++nt) {
            int col = nt * 16 + am;
            if (col < C_) {
                int k = hh * C_ + col;
#pragma unroll
                for (int i = 0; i < 4; ++i) {
                    int row = aq * 4 + i;
                    float val = accv[nt][i] + Ored[0][row * 144 + col]
                              + Ored[1][row * 144 + col] + Ored[2][row * 144 + col];
                    hpb[((size_t)(k >> 5) * M_ + m0 + row) * 32 + (k & 31)] = f2bf(val * Linv[row]);
                }
            }
        }
    }
    if (hh == 3) {   // zero pad k = 516..543
        for (int idx = t; idx < 16 * 28; idx += 256) {
            int rr = idx / 28, cc = 516 + (idx - rr * 28);
            hpb[((size_t)(cc >> 5) * M_ + m0 + rr) * 32 + (cc & 31)] = 0;
        }
    }
}

// ---------------- K4: node MLP (tile-major A and B) + skip -> cpost[M][CP] ----------------
__global__ __launch_bounds__(256) void k_mlp(
    const ushort_t* __restrict__ hpb,
    const ushort_t* __restrict__ W1T, const float* __restrict__ b1,
    const ushort_t* __restrict__ W2T, const float* __restrict__ b2,
    const float* __restrict__ x, const float* __restrict__ h,
    const int* __restrict__ nb, const int* __restrict__ nn,
    float* __restrict__ cpost) {
    __shared__ alignas(16) ushort_t Hs[16 * 168];
    const int t = threadIdx.x;
    const int m0 = blockIdx.x * 16;
    const int lane = t & 63, w = t >> 6;
    const int am = lane & 15, aq = lane >> 4;
    f32x4 acc[3];
#pragma unroll
    for (int j = 0; j < 3; ++j) acc[j] = f32x4{0.f, 0.f, 0.f, 0.f};
    for (int kt = 0; kt < 17; ++kt) {
        short8 af = *reinterpret_cast<const short8*>(&hpb[((size_t)kt * M_ + m0 + am) * 32 + aq * 8]);
#pragma unroll
        for (int j = 0; j < 3; ++j) {
            int nt = w + 4 * j;
            if (nt < 9) {
                short8 bf = *reinterpret_cast<const short8*>(
                    &W1T[((size_t)kt * 144 + nt * 16 + am) * 32 + aq * 8]);
                acc[j] = __builtin_amdgcn_mfma_f32_16x16x32_bf16(af, bf, acc[j], 0, 0, 0);
            }
        }
    }
#pragma unroll
    for (int j = 0; j < 3; ++j) {
        int nt = w + 4 * j;
        if (nt < 9) {
            int col = nt * 16 + am;
            float bb = (col < C_) ? b1[col] : 0.f;
#pragma unroll
            for (int i = 0; i < 4; ++i) {
                int row = aq * 4 + i;
                float v = (col < C_) ? fmaxf(acc[j][i] + bb, 0.f) : 0.f;
                Hs[row * 168 + col] = f2bf(v);
            }
        }
    }
    { int row = t >> 4, cc = 144 + (t & 15); Hs[row * 168 + cc] = 0; }
    __syncthreads();
    f32x4 acc2[3];
#pragma unroll
    for (int j = 0; j < 3; ++j) acc2[j] = f32x4{0.f, 0.f, 0.f, 0.f};
    for (int kt = 0; kt < 5; ++kt) {
        short8 af = *reinterpret_cast<const short8*>(&Hs[am * 168 + kt * 32 + aq * 8]);
#pragma unroll
        for (int j = 0; j < 3; ++j) {
            int nt = w + 4 * j;
            if (nt < 9) {
                short8 bf = *reinterpret_cast<const short8*>(
                    &W2T[((size_t)kt * 144 + nt * 16 + am) * 32 + aq * 8]);
                acc2[j] = __builtin_amdgcn_mfma_f32_16x16x32_bf16(af, bf, acc2[j], 0, 0, 0);
            }
        }
    }
#pragma unroll
    for (int j = 0; j < 3; ++j) {
        int nt = w + 4 * j;
        if (nt < 9) {
            int col = nt * 16 + am;
            if (col < C_) {
                float bb = b2[col];
#pragma unroll
                for (int i = 0; i < 4; ++i) {
                    int m = m0 + aq * 4 + i;
                    int b = nb[m], n = nn[m];
                    float sk = (col < 65) ? x[(b * N_ + n) * 65 + col]
                                          : h[(b * N_ + n) * D_ + (col - 65)];
                    cpost[(size_t)m * CP + col] = acc2[j][i] + bb + sk;
                }
            }
        }
    }
    if (t < 48) {
        int rr = t / 3, cc = 129 + (t - (t / 3) * 3);
        cpost[(size_t)(m0 + rr) * CP + cc] = 0.f;
    }
}

// ---------------- K5a: build A tile-major from cpost rows ----------------
__global__ __launch_bounds__(256) void k_arow(const float* __restrict__ src,
                                              const float* __restrict__ qv,
                                              ushort_t* __restrict__ A) {
    __shared__ float sq[CP];
    __shared__ float qs[QV_];
    const int t = threadIdx.x;
    const int m = blockIdx.x;
    if (t < CP) sq[t] = src[(size_t)m * CP + t];
    if (t >= 224) qs[t - 224] = qv[m * QV_ + (t - 224)];
    __syncthreads();
    for (int k = t; k < 4224; k += 256) {
        int d = k / 132, i = k - d * 132;
        A[((size_t)(k >> 5) * M_ + m) * 32 + (k & 31)] = f2bf(qs[d] * sq[i]);
    }
    if (t < QV_) A[((size_t)132 * M_ + m) * 32 + t] = f2bf(qs[t]);
}

// ---------------- K5a2: build A for cand pass — sel row built inline from x,h,pru ----------------
__global__ __launch_bounds__(256) void k_arow2(const float* __restrict__ x,
                                               const float* __restrict__ h,
                                               const int* __restrict__ nb,
                                               const int* __restrict__ nn,
                                               const float* __restrict__ pru,
                                               const float* __restrict__ qv,
                                               ushort_t* __restrict__ A) {
    __shared__ float sq[132];
    __shared__ float qs[QV_];
    const int t = threadIdx.x;
    const int m = blockIdx.x;
    const int b = nb[m], n = nn[m];
    if (t < 65) sq[t] = x[(b * N_ + n) * 65 + t];
    else if (t < 129) {
        int o = t - 65;
        const size_t S = (size_t)M_ * 128;
        size_t base = (size_t)m * 128 + o;
        float s = 0.f;
#pragma unroll
        for (int z = 0; z < ZS; ++z) s += pru[z * S + base];
        float rv = 1.f / (1.f + __expf(-s));
        sq[t] = rv * h[(b * N_ + n) * D_ + o];
    } else if (t < 132) sq[t] = 0.f;
    if (t >= 224) qs[t - 224] = qv[m * QV_ + (t - 224)];
    __syncthreads();
    for (int k = t; k < 4224; k += 256) {
        int d = k / 132, i = k - d * 132;
        A[((size_t)(k >> 5) * M_ + m) * 32 + (k & 31)] = f2bf(qs[d] * sq[i]);
    }
    if (t < QV_) A[((size_t)132 * M_ + m) * 32 + t] = f2bf(qs[t]);
}

// ---------------- K5b: hyper GEMM, tile-major operands, 32-row m-tiles, ZS-way k-split ----------
template<int NN>
__global__ __launch_bounds__(256) void k_gemm(const ushort_t* __restrict__ A,
                                              const ushort_t* __restrict__ WT,
                                              float* __restrict__ part) {
    const int t = threadIdx.x;
    const int m0 = blockIdx.x * 32;
    const int z = blockIdx.y;
    const int lane = t & 63, w = t >> 6;
    const int am = lane & 15, aq = lane >> 4;
    constexpr int NTpW = NN / 64;
    const int ktb = z * 17;
    const int kte = (ktb + 17 < NKT) ? ktb + 17 : NKT;
    f32x4 acc[2][NTpW];
#pragma unroll
    for (int r2 = 0; r2 < 2; ++r2)
#pragma unroll
        for (int j = 0; j < NTpW; ++j) acc[r2][j] = f32x4{0.f, 0.f, 0.f, 0.f};
    for (int kt = ktb; kt < kte; ++kt) {
        const ushort_t* Ab = A + ((size_t)kt * M_ + m0) * 32 + aq * 8;
        short8 a0 = *reinterpret_cast<const short8*>(Ab + am * 32);
        short8 a1 = *reinterpret_cast<const short8*>(Ab + (am + 16) * 32);
        const ushort_t* Bb = WT + (size_t)kt * NN * 32 + am * 32 + aq * 8;
#pragma unroll
        for (int j = 0; j < NTpW; ++j) {
            int nt = w + 4 * j;
            short8 bf = *reinterpret_cast<const short8*>(Bb + nt * 16 * 32);
            acc[0][j] = __builtin_amdgcn_mfma_f32_16x16x32_bf16(a0, bf, acc[0][j], 0, 0, 0);
            acc[1][j] = __builtin_amdgcn_mfma_f32_16x16x32_bf16(a1, bf, acc[1][j], 0, 0, 0);
        }
    }
#pragma unroll
    for (int j = 0; j < NTpW; ++j) {
        int n = (w + 4 * j) * 16 + am;
#pragma unroll
        for (int r2 = 0; r2 < 2; ++r2)
#pragma unroll
            for (int i = 0; i < 4; ++i) {
                int m = m0 + r2 * 16 + aq * 4 + i;
                part[((size_t)z * M_ + m) * NN + n] = acc[r2][j][i];
            }
    }
}

// ---------------- K5d: final gate (r-gate recomputed inline) ----------------
__global__ void k_final(const float* __restrict__ pru, const float* __restrict__ pc,
                        const float* __restrict__ h,
                        const int* __restrict__ nb, const int* __restrict__ nn,
                        float* __restrict__ out) {
    int idx = blockIdx.x * 256 + threadIdx.x;
    if (idx >= M_ * D_) return;
    int m = idx >> 6, o = idx & 63;
    const size_t Su = (size_t)M_ * 128;
    size_t br_ = (size_t)m * 128 + o;
    size_t bu = br_ + 64;
    float sr = 0.f, su = 0.f;
#pragma unroll
    for (int z = 0; z < ZS; ++z) { sr += pru[z * Su + br_]; su += pru[z * Su + bu]; }
    float rv = 1.f / (1.f + __expf(-sr));
    float uv = 1.f / (1.f + __expf(-su));
    const size_t Sc = (size_t)M_ * 64;
    size_t bcx = (size_t)m * 64 + o;
    float sc = 0.f;
#pragma unroll
    for (int z = 0; z < ZS; ++z) sc += pc[z * Sc + bcx];
    float cand = tanhf(sc);
    int b = nb[m], n = nn[m];
    float hn = rv * h[(b * N_ + n) * D_ + o];
    out[idx] = (1.f - uv) * hn + uv * cand;
}

extern "C" void kernel_launch(void* const* d_in, const int* in_sizes, int n_in,
                              void* d_out, int out_size, void* d_ws, size_t ws_size,
                              hipStream_t stream) {
    const float* x   = (const float*)d_in[0];
    const float* h   = (const float*)d_in[1];
    const float* qv  = (const float*)d_in[2];
    const int*   adj = (const int*)d_in[3];
    const int*   nb  = (const int*)d_in[4];
    const int*   nn  = (const int*)d_in[5];
    const float* Wq  = (const float*)d_in[6];
    const float* bq  = (const float*)d_in[7];
    const float* Wk  = (const float*)d_in[8];
    const float* bk  = (const float*)d_in[9];
    const float* Wv  = (const float*)d_in[10];
    const float* bv  = (const float*)d_in[11];
    const float* W1  = (const float*)d_in[12];
    const float* b1  = (const float*)d_in[13];
    const float* W2  = (const float*)d_in[14];
    const float* b2  = (const float*)d_in[15];
    const float* Wr  = (const float*)d_in[16];
    const float* br  = (const float*)d_in[17];
    const float* Wu  = (const float*)d_in[18];
    const float* bu  = (const float*)d_in[19];
    const float* Wc  = (const float*)d_in[20];
    const float* bc  = (const float*)d_in[21];
    float* ws = (float*)d_ws;
    float* out = (float*)d_out;

    ushort_t* cb   = (ushort_t*)(ws + o_cb);
    ushort_t* qb   = (ushort_t*)(ws + o_qb);
    ushort_t* kb   = (ushort_t*)(ws + o_kb);
    u64*      ab   = (u64*)(ws + o_adjb);
    ushort_t* wqk  = (ushort_t*)(ws + o_wqk);
    ushort_t* wvt  = (ushort_t*)(ws + o_wvt);
    ushort_t* vTg  = (ushort_t*)(ws + o_vT);
    ushort_t* hpb  = (ushort_t*)(ws + o_hpb);
    float* cpost = ws + o_cpost;
    ushort_t* W1T  = (ushort_t*)(ws + o_W1T);
    ushort_t* W2T  = (ushort_t*)(ws + o_W2T);
    ushort_t* wtru = (ushort_t*)(ws + o_wtru);
    ushort_t* wtc  = (ushort_t*)(ws + o_wtc);
    ushort_t* Abuf = (ushort_t*)(ws + o_A);
    float* pru   = ws + o_pru;
    float* pc    = ws + o_pc2;

    k_prep<<<(SEG6 + 255) / 256, 256, 0, stream>>>(
        x, h, Wq, bq, Wk, bk, Wv, bv, W1, W2, Wr, br, Wu, bu, Wc, bc, adj,
        cb, wqk, wvt, W1T, W2T, wtru, wtc, ab);
    k_qkv<<<dim3(NG / 16, H_), 256, 0, stream>>>(cb, wqk, wvt, qb, kb, vTg);
    k_attn<<<dim3(M_ / 16, H_), 256, 0, stream>>>(qb, kb, vTg, ab, nb, nn, hpb);
    k_mlp<<<M_ / 16, 256, 0, stream>>>(hpb, W1T, b1, W2T, b2, x, h, nb, nn, cpost);
    k_arow<<<M_, 256, 0, stream>>>(cpost, qv, Abuf);
    k_gemm<128><<<dim3(M_ / 32, ZS), 256, 0, stream>>>(Abuf, wtru, pru);
    k_arow2<<<M_, 256, 0, stream>>>(x, h, nb, nn, pru, qv, Abuf);
    k_gemm<64><<<dim3(M_ / 32, ZS), 256, 0, stream>>>(Abuf, wtc, pc);
    k_final<<<(M_ * D_ + 255) / 256, 256, 0, stream>>>(pru, pc, h, nb, nn, out);
}

// Round 20
// 256.249 us; speedup vs baseline: 1.0232x; 1.0066x over previous
//
#include <hip/hip_runtime.h>

#define DEVINL __device__ __forceinline__

typedef unsigned short ushort_t;
typedef unsigned long long u64;
typedef __attribute__((ext_vector_type(8))) short short8;
typedef __attribute__((ext_vector_type(8))) unsigned short ushort8;
typedef __attribute__((ext_vector_type(4))) float f32x4;

constexpr int B_ = 8, N_ = 1024, D_ = 64, H_ = 4, QV_ = 32;
constexpr int C_ = 129, K_ = 16, M_ = 4096;
constexpr int CP = 132;              // cpost fp32 row stride
constexpr int NG = B_ * N_;          // 8192 nodes
constexpr int CBS = 160;             // cb logical row width (5 k-tiles; k=129 bias-1.0)
constexpr int VTN = 144;             // vT padded n-dim (9 MFMA n-tiles)
constexpr int KT = 4256;             // hyper GEMM K (133 tiles of 32)
constexpr int NKT = 133;
constexpr int ZS = 8;                // k-split chunks (17 k-tiles each)
constexpr int HPS = 544;             // hpb logical row width (17 k-tiles)
constexpr int NCH = NG / 32;         // 256 node-chunks per head (vT tile-major)
constexpr int PBS = 1096;            // Pball row stride (1024 + 72-style pad; 2-way banks)

// ---- workspace layout (float offsets) ----
constexpr size_t o_cb    = 0;                                   // [5][NG][32] ushort
constexpr size_t o_qb    = o_cb  + (size_t)NG * CBS / 2;        // H*NG*16 ushort
constexpr size_t o_kb    = o_qb  + (size_t)H_ * NG * 16 / 2;    // H*NG*16 ushort
constexpr size_t o_adjb  = o_kb  + (size_t)H_ * NG * 16 / 2;    // 1024*16 u64
constexpr size_t o_wqk   = o_adjb + 32768;                      // [H][5][32][32] ushort
constexpr size_t o_wvt   = o_wqk + (size_t)H_ * 32 * CBS / 2;   // [H][5][144][32] ushort
constexpr size_t o_vT    = o_wvt + (size_t)H_ * VTN * CBS / 2;  // [H][NCH][144][32] ushort
constexpr size_t o_hpb   = o_vT  + (size_t)H_ * VTN * NG / 2;   // [17][M][32] ushort
constexpr size_t o_cpost = o_hpb + (size_t)M_ * HPS / 2;        // M*CP fp32
constexpr size_t o_W1T   = o_cpost + (size_t)M_ * CP;           // [17][144][32] ushort
constexpr size_t o_W2T   = o_W1T + (size_t)144 * HPS / 2;       // [5][144][32] ushort
constexpr size_t o_wtru  = o_W2T + (size_t)144 * 160 / 2;       // [NKT][128][32] ushort
constexpr size_t o_wtc   = o_wtru + (size_t)128 * KT / 2;       // [NKT][64][32] ushort
constexpr size_t o_A     = o_wtc + (size_t)64 * KT / 2;         // [NKT][M][32] ushort
constexpr size_t o_pru   = o_A + (size_t)M_ * KT / 2;           // ZS*M*128 fp32
constexpr size_t o_pc2   = o_pru + (size_t)ZS * M_ * 128;       // ZS*M*64 fp32

// fused-prep segment bounds (all multiples of 64 -> wave-uniform branches)
constexpr int SEG0 = NG * CBS;                  // cb
constexpr int SEG1 = SEG0 + H_ * 32 * CBS;      // wqk
constexpr int SEG2 = SEG1 + H_ * VTN * CBS;     // wvt
constexpr int SEG3 = SEG2 + 144 * HPS;          // W1T
constexpr int SEG4 = SEG3 + 144 * 160;          // W2T
constexpr int SEG5 = SEG4 + 192 * KT;           // wtru+wtc (tile-major)
constexpr int SEG6 = SEG5 + 1024 * 16 * 64;     // adjb ballot slots

DEVINL float4 ld4(const float* p) { return *reinterpret_cast<const float4*>(p); }
DEVINL void st4(float* p, float4 v) { *reinterpret_cast<float4*>(p) = v; }
DEVINL ushort_t f2bf(float f) {           // RNE fp32->bf16
    unsigned int u = __float_as_uint(f);
    u += 0x7FFFu + ((u >> 16) & 1u);
    return (ushort_t)(u >> 16);
}

// ---------------- K0: fused prep — ALL GEMM operands tile-major [kt][row][32] ----------------
__global__ void k_prep(const float* __restrict__ x, const float* __restrict__ h,
                       const float* __restrict__ Wq, const float* __restrict__ bq,
                       const float* __restrict__ Wk, const float* __restrict__ bk,
                       const float* __restrict__ Wv, const float* __restrict__ bv,
                       const float* __restrict__ W1, const float* __restrict__ W2,
                       const float* __restrict__ Wr, const float* __restrict__ br,
                       const float* __restrict__ Wu, const float* __restrict__ bu,
                       const float* __restrict__ Wc, const float* __restrict__ bc,
                       const int* __restrict__ adj,
                       ushort_t* __restrict__ cb, ushort_t* __restrict__ wqk,
                       ushort_t* __restrict__ wvt, ushort_t* __restrict__ W1T,
                       ushort_t* __restrict__ W2T, ushort_t* __restrict__ wtru,
                       ushort_t* __restrict__ wtc, u64* __restrict__ ab) {
    int idx = blockIdx.x * 256 + threadIdx.x;
    if (idx < SEG0) {
        int g = idx / CBS, kk = idx - g * CBS;
        float v;
        if (kk < 65) v = x[g * 65 + kk];
        else if (kk < 129) v = h[g * 64 + (kk - 65)];
        else if (kk == 129) v = 1.0f;
        else v = 0.f;
        cb[((size_t)(kk >> 5) * NG + g) * 32 + (kk & 31)] = f2bf(v);
    } else if (idx < SEG1) {
        int j = idx - SEG0;
        int hh = j / (32 * CBS); int rem = j - hh * 32 * CBS;
        int o = rem / CBS, kk = rem - o * CBS;
        float v = 0.f;
        if (o < 16) {
            if (kk < 129) v = Wq[(size_t)(hh * C_ + kk) * K_ + o];
            else if (kk == 129) v = bq[hh * K_ + o];
        } else {
            int o2 = o - 16;
            if (kk < 129) v = Wk[(size_t)(hh * C_ + kk) * K_ + o2];
            else if (kk == 129) v = bk[hh * K_ + o2];
        }
        wqk[((size_t)(hh * 5 + (kk >> 5)) * 32 + o) * 32 + (kk & 31)] = f2bf(v);
    } else if (idx < SEG2) {
        int j = idx - SEG1;
        int hh = j / (VTN * CBS); int rem = j - hh * VTN * CBS;
        int n = rem / CBS, kk = rem - n * CBS;
        float v = 0.f;
        if (n < C_) {
            if (kk < 129) v = Wv[(size_t)(hh * C_ + kk) * C_ + n];
            else if (kk == 129) v = bv[hh * C_ + n];
        }
        wvt[((size_t)(hh * 5 + (kk >> 5)) * 144 + n) * 32 + (kk & 31)] = f2bf(v);
    } else if (idx < SEG3) {
        int j = idx - SEG2;
        int o = j / HPS, k = j - o * HPS;
        float v = (o < C_ && k < 516) ? W1[(size_t)k * C_ + o] : 0.f;
        W1T[((size_t)(k >> 5) * 144 + o) * 32 + (k & 31)] = f2bf(v);
    } else if (idx < SEG4) {
        int j = idx - SEG3;
        int o = j / 160, k = j - o * 160;
        float v = (o < C_ && k < C_) ? W2[(size_t)k * C_ + o] : 0.f;
        W2T[((size_t)(k >> 5) * 144 + o) * 32 + (k & 31)] = f2bf(v);
    } else if (idx < SEG5) {
        int j = idx - SEG4;
        int row = j / KT, k = j - row * KT;
        float v;
        if (k >= 4224) {
            int d = k - 4224;
            if (row < 64) v = br[d * 64 + row];
            else if (row < 128) v = bu[d * 64 + row - 64];
            else v = bc[d * 64 + row - 128];
        } else {
            int d = k / 132, i = k - d * 132;
            if (i >= 129) v = 0.f;
            else if (row < 64) v = Wr[(size_t)(d * 129 + i) * 64 + row];
            else if (row < 128) v = Wu[(size_t)(d * 129 + i) * 64 + row - 64];
            else v = Wc[(size_t)(d * 129 + i) * 64 + row - 128];
        }
        int kt = k >> 5, kj = k & 31;
        if (row < 128) wtru[((size_t)kt * 128 + row) * 32 + kj] = f2bf(v);
        else wtc[((size_t)kt * 64 + (row - 128)) * 32 + kj] = f2bf(v);
    } else if (idx < SEG6) {
        int j = idx - SEG5;
        int word = j >> 6, lane = j & 63;
        int row = word >> 4, wj = word & 15;
        u64 m = __ballot(adj[(size_t)row * N_ + wj * 64 + lane] != 0);
        if (lane == 0) ab[word] = m;
    }
}

// ---------------- K1: MFMA projections (tile-major); vT written tile-major ----------------
__global__ __launch_bounds__(256) void k_qkv(
    const ushort_t* __restrict__ cb, const ushort_t* __restrict__ wqk,
    const ushort_t* __restrict__ wvt,
    ushort_t* __restrict__ qbo, ushort_t* __restrict__ kbo, ushort_t* __restrict__ vTg) {
    const int t = threadIdx.x;
    const int g0 = blockIdx.x * 16;
    const int hh = blockIdx.y;
    const int lane = t & 63, w = t >> 6;
    const int am = lane & 15, aq = lane >> 4;
    short8 cbf[5];
#pragma unroll
    for (int kt = 0; kt < 5; ++kt)
        cbf[kt] = *reinterpret_cast<const short8*>(&cb[((size_t)kt * NG + g0 + am) * 32 + aq * 8]);
#pragma unroll
    for (int s = 0; s < 3; ++s) {
        int u = w + 4 * s;
        if (u >= 11) break;
        f32x4 acc = f32x4{0.f, 0.f, 0.f, 0.f};
        if (u < 2) {
#pragma unroll
            for (int kt = 0; kt < 5; ++kt) {
                short8 bf = *reinterpret_cast<const short8*>(
                    &wqk[((size_t)(hh * 5 + kt) * 32 + u * 16 + am) * 32 + aq * 8]);
                acc = __builtin_amdgcn_mfma_f32_16x16x32_bf16(cbf[kt], bf, acc, 0, 0, 0);
            }
            ushort_t* dst = u ? kbo : qbo;
#pragma unroll
            for (int i = 0; i < 4; ++i)
                dst[(size_t)(hh * NG + g0 + aq * 4 + i) * 16 + am] = f2bf(acc[i]);
        } else {
            int vt = u - 2;
#pragma unroll
            for (int kt = 0; kt < 5; ++kt) {
                short8 af = *reinterpret_cast<const short8*>(
                    &wvt[((size_t)(hh * 5 + kt) * 144 + vt * 16 + am) * 32 + aq * 8]);
                acc = __builtin_amdgcn_mfma_f32_16x16x32_bf16(af, cbf[kt], acc, 0, 0, 0);
            }
            // C-layout: row (aq*4+i) = feature (A's M dim), col (am) = node (B's N dim)
            const int g = g0 + am;                 // node; g>>5 constant within block
#pragma unroll
            for (int i = 0; i < 4; ++i) {
                int feat = vt * 16 + aq * 4 + i;
                vTg[(((size_t)hh * NCH + (g >> 5)) * 144 + feat) * 32 + (g & 31)] = f2bf(acc[i]);
            }
        }
    }
}

// ---------------- K3: attention v3 — two-phase, reduction-free ----------------
// Phase 1: wave w computes P for col-tiles {w,w+4,w+8,w+12} into block-wide Pball.
// Phase 2: wave w owns n-tiles {w,w+4,w+8}; full-K MFMA chains; no cross-wave O reduce.
__global__ __launch_bounds__(256) void k_attn(
    const ushort_t* __restrict__ qb, const ushort_t* __restrict__ kb,
    const ushort_t* __restrict__ vTg, const u64* __restrict__ adjb,
    const int* __restrict__ nodes_b, const int* __restrict__ nodes_n,
    ushort_t* __restrict__ hpb) {
    __shared__ u64 Msk[16][16];
    __shared__ alignas(16) ushort_t Pball[16 * PBS];
    __shared__ float Lpart[4][16];
    __shared__ int Nrow[16];
    const int t = threadIdx.x;
    const int bi = blockIdx.x;
    const int mx = ((bi & 7) << 5) + (bi >> 3);   // XCD i <- batch i
    const int m0 = mx * 16;
    const int hh = blockIdx.y;
    const int b = nodes_b[m0];
    if (t < 16) Nrow[t] = nodes_n[m0 + t];
    __syncthreads();
    { int r = t >> 4, wj = t & 15; Msk[r][wj] = adjb[Nrow[r] * 16 + wj]; }
    const int lane = t & 63, w = t >> 6;
    const int am = lane & 15, aq = lane >> 4;
    short8 qf = short8{0, 0, 0, 0, 0, 0, 0, 0};
    if (aq < 2)
        qf = *reinterpret_cast<const short8*>(&qb[(size_t)(hh * NG + b * N_ + Nrow[am]) * 16 + aq * 8]);
    __syncthreads();
    const ushort_t* kbase = kb + ((size_t)hh * NG + b * N_) * 16;
    const ushort_t* vbase = vTg + ((size_t)hh * NCH + b * 32) * 144 * 32;
    float lsum[4] = {0.f, 0.f, 0.f, 0.f};

    // ---- phase 1: QK + masked-leaky-exp -> Pball (4 independent tiles per wave) ----
#pragma unroll
    for (int ti = 0; ti < 4; ++ti) {
        const int tile = w + 4 * ti;
        const int c0 = tile * 64;
        u64 mrow[4];
#pragma unroll
        for (int i = 0; i < 4; ++i) mrow[i] = Msk[aq * 4 + i][tile];
#pragma unroll
        for (int nt = 0; nt < 4; ++nt) {
            int col = c0 + nt * 16 + am;
            short8 bf = short8{0, 0, 0, 0, 0, 0, 0, 0};
            if (aq < 2)
                bf = *reinterpret_cast<const short8*>(&kbase[(size_t)col * 16 + aq * 8]);
            f32x4 sv = __builtin_amdgcn_mfma_f32_16x16x32_bf16(qf, bf, f32x4{0.f, 0.f, 0.f, 0.f}, 0, 0, 0);
#pragma unroll
            for (int i = 0; i < 4; ++i) {
                float s = sv[i] * 0.25f;
                s = (s >= 0.f) ? s : 0.2f * s;
                float p = ((mrow[i] >> (nt * 16 + am)) & 1ull) ? __expf(s) : 0.f;
                lsum[i] += p;
                Pball[(aq * 4 + i) * PBS + col] = f2bf(p);
            }
        }
    }
#pragma unroll
    for (int i = 0; i < 4; ++i) {
        float v = lsum[i];
        v += __shfl_xor(v, 1); v += __shfl_xor(v, 2);
        v += __shfl_xor(v, 4); v += __shfl_xor(v, 8);
        if (am == 0) Lpart[w][aq * 4 + i] = v;
    }
    __syncthreads();
    // per-lane inverse row sums (rows aq*4+i)
    float linv[4];
#pragma unroll
    for (int i = 0; i < 4; ++i) {
        int row = aq * 4 + i;
        float s = Lpart[0][row] + Lpart[1][row] + Lpart[2][row] + Lpart[3][row];
        linv[i] = (s > 0.f) ? 1.f / s : 0.f;
    }

    // ---- phase 2: PV — wave w owns n-tiles {w, w+4, w+8}; full-K chains ----
    f32x4 acc[3];
#pragma unroll
    for (int j = 0; j < 3; ++j) acc[j] = f32x4{0.f, 0.f, 0.f, 0.f};
    for (int ck = 0; ck < 32; ++ck) {
        short8 af = *reinterpret_cast<const short8*>(&Pball[am * PBS + ck * 32 + aq * 8]);
        const ushort_t* vch = vbase + (size_t)ck * 144 * 32;
#pragma unroll
        for (int j = 0; j < 3; ++j) {
            int nt = w + 4 * j;
            if (nt < 9) {
                short8 bf = *reinterpret_cast<const short8*>(&vch[(size_t)(nt * 16 + am) * 32 + aq * 8]);
                acc[j] = __builtin_amdgcn_mfma_f32_16x16x32_bf16(af, bf, acc[j], 0, 0, 0);
            }
        }
    }
#pragma unroll
    for (int j = 0; j < 3; ++j) {
        int nt = w + 4 * j;
        if (nt < 9) {
            int col = nt * 16 + am;
            if (col < C_) {
                int k = hh * C_ + col;
#pragma unroll
                for (int i = 0; i < 4; ++i) {
                    int row = aq * 4 + i;
                    hpb[((size_t)(k >> 5) * M_ + m0 + row) * 32 + (k & 31)] = f2bf(acc[j][i] * linv[i]);
                }
            }
        }
    }
    if (hh == 3) {   // zero pad k = 516..543
        for (int idx = t; idx < 16 * 28; idx += 256) {
            int rr = idx / 28, cc = 516 + (idx - rr * 28);
            hpb[((size_t)(cc >> 5) * M_ + m0 + rr) * 32 + (cc & 31)] = 0;
        }
    }
}

// ---------------- K4: node MLP (tile-major A and B) + skip -> cpost[M][CP] ----------------
__global__ __launch_bounds__(256) void k_mlp(
    const ushort_t* __restrict__ hpb,
    const ushort_t* __restrict__ W1T, const float* __restrict__ b1,
    const ushort_t* __restrict__ W2T, const float* __restrict__ b2,
    const float* __restrict__ x, const float* __restrict__ h,
    const int* __restrict__ nb, const int* __restrict__ nn,
    float* __restrict__ cpost) {
    __shared__ alignas(16) ushort_t Hs[16 * 168];
    const int t = threadIdx.x;
    const int m0 = blockIdx.x * 16;
    const int lane = t & 63, w = t >> 6;
    const int am = lane & 15, aq = lane >> 4;
    f32x4 acc[3];
#pragma unroll
    for (int j = 0; j < 3; ++j) acc[j] = f32x4{0.f, 0.f, 0.f, 0.f};
    for (int kt = 0; kt < 17; ++kt) {
        short8 af = *reinterpret_cast<const short8*>(&hpb[((size_t)kt * M_ + m0 + am) * 32 + aq * 8]);
#pragma unroll
        for (int j = 0; j < 3; ++j) {
            int nt = w + 4 * j;
            if (nt < 9) {
                short8 bf = *reinterpret_cast<const short8*>(
                    &W1T[((size_t)kt * 144 + nt * 16 + am) * 32 + aq * 8]);
                acc[j] = __builtin_amdgcn_mfma_f32_16x16x32_bf16(af, bf, acc[j], 0, 0, 0);
            }
        }
    }
#pragma unroll
    for (int j = 0; j < 3; ++j) {
        int nt = w + 4 * j;
        if (nt < 9) {
            int col = nt * 16 + am;
            float bb = (col < C_) ? b1[col] : 0.f;
#pragma unroll
            for (int i = 0; i < 4; ++i) {
                int row = aq * 4 + i;
                float v = (col < C_) ? fmaxf(acc[j][i] + bb, 0.f) : 0.f;
                Hs[row * 168 + col] = f2bf(v);
            }
        }
    }
    { int row = t >> 4, cc = 144 + (t & 15); Hs[row * 168 + cc] = 0; }
    __syncthreads();
    f32x4 acc2[3];
#pragma unroll
    for (int j = 0; j < 3; ++j) acc2[j] = f32x4{0.f, 0.f, 0.f, 0.f};
    for (int kt = 0; kt < 5; ++kt) {
        short8 af = *reinterpret_cast<const short8*>(&Hs[am * 168 + kt * 32 + aq * 8]);
#pragma unroll
        for (int j = 0; j < 3; ++j) {
            int nt = w + 4 * j;
            if (nt < 9) {
                short8 bf = *reinterpret_cast<const short8*>(
                    &W2T[((size_t)kt * 144 + nt * 16 + am) * 32 + aq * 8]);
                acc2[j] = __builtin_amdgcn_mfma_f32_16x16x32_bf16(af, bf, acc2[j], 0, 0, 0);
            }
        }
    }
#pragma unroll
    for (int j = 0; j < 3; ++j) {
        int nt = w + 4 * j;
        if (nt < 9) {
            int col = nt * 16 + am;
            if (col < C_) {
                float bb = b2[col];
#pragma unroll
                for (int i = 0; i < 4; ++i) {
                    int m = m0 + aq * 4 + i;
                    int b = nb[m], n = nn[m];
                    float sk = (col < 65) ? x[(b * N_ + n) * 65 + col]
                                          : h[(b * N_ + n) * D_ + (col - 65)];
                    cpost[(size_t)m * CP + col] = acc2[j][i] + bb + sk;
                }
            }
        }
    }
    if (t < 48) {
        int rr = t / 3, cc = 129 + (t - (t / 3) * 3);
        cpost[(size_t)(m0 + rr) * CP + cc] = 0.f;
    }
}

// ---------------- K5a: build A tile-major from cpost rows ----------------
__global__ __launch_bounds__(256) void k_arow(const float* __restrict__ src,
                                              const float* __restrict__ qv,
                                              ushort_t* __restrict__ A) {
    __shared__ float sq[CP];
    __shared__ float qs[QV_];
    const int t = threadIdx.x;
    const int m = blockIdx.x;
    if (t < CP) sq[t] = src[(size_t)m * CP + t];
    if (t >= 224) qs[t - 224] = qv[m * QV_ + (t - 224)];
    __syncthreads();
    for (int k = t; k < 4224; k += 256) {
        int d = k / 132, i = k - d * 132;
        A[((size_t)(k >> 5) * M_ + m) * 32 + (k & 31)] = f2bf(qs[d] * sq[i]);
    }
    if (t < QV_) A[((size_t)132 * M_ + m) * 32 + t] = f2bf(qs[t]);
}

// ---------------- K5a2: build A for cand pass — sel row built inline from x,h,pru ----------------
__global__ __launch_bounds__(256) void k_arow2(const float* __restrict__ x,
                                               const float* __restrict__ h,
                                               const int* __restrict__ nb,
                                               const int* __restrict__ nn,
                                               const float* __restrict__ pru,
                                               const float* __restrict__ qv,
                                               ushort_t* __restrict__ A) {
    __shared__ float sq[132];
    __shared__ float qs[QV_];
    const int t = threadIdx.x;
    const int m = blockIdx.x;
    const int b = nb[m], n = nn[m];
    if (t < 65) sq[t] = x[(b * N_ + n) * 65 + t];
    else if (t < 129) {
        int o = t - 65;
        const size_t S = (size_t)M_ * 128;
        size_t base = (size_t)m * 128 + o;
        float s = 0.f;
#pragma unroll
        for (int z = 0; z < ZS; ++z) s += pru[z * S + base];
        float rv = 1.f / (1.f + __expf(-s));
        sq[t] = rv * h[(b * N_ + n) * D_ + o];
    } else if (t < 132) sq[t] = 0.f;
    if (t >= 224) qs[t - 224] = qv[m * QV_ + (t - 224)];
    __syncthreads();
    for (int k = t; k < 4224; k += 256) {
        int d = k / 132, i = k - d * 132;
        A[((size_t)(k >> 5) * M_ + m) * 32 + (k & 31)] = f2bf(qs[d] * sq[i]);
    }
    if (t < QV_) A[((size_t)132 * M_ + m) * 32 + t] = f2bf(qs[t]);
}

// ---------------- K5b: hyper GEMM, tile-major operands, 32-row m-tiles, ZS-way k-split ----------
template<int NN>
__global__ __launch_bounds__(256) void k_gemm(const ushort_t* __restrict__ A,
                                              const ushort_t* __restrict__ WT,
                                              float* __restrict__ part) {
    const int t = threadIdx.x;
    const int m0 = blockIdx.x * 32;
    const int z = blockIdx.y;
    const int lane = t & 63, w = t >> 6;
    const int am = lane & 15, aq = lane >> 4;
    constexpr int NTpW = NN / 64;
    const int ktb = z * 17;
    const int kte = (ktb + 17 < NKT) ? ktb + 17 : NKT;
    f32x4 acc[2][NTpW];
#pragma unroll
    for (int r2 = 0; r2 < 2; ++r2)
#pragma unroll
        for (int j = 0; j < NTpW; ++j) acc[r2][j] = f32x4{0.f, 0.f, 0.f, 0.f};
    for (int kt = ktb; kt < kte; ++kt) {
        const ushort_t* Ab = A + ((size_t)kt * M_ + m0) * 32 + aq * 8;
        short8 a0 = *reinterpret_cast<const short8*>(Ab + am * 32);
        short8 a1 = *reinterpret_cast<const short8*>(Ab + (am + 16) * 32);
        const ushort_t* Bb = WT + (size_t)kt * NN * 32 + am * 32 + aq * 8;
#pragma unroll
        for (int j = 0; j < NTpW; ++j) {
            int nt = w + 4 * j;
            short8 bf = *reinterpret_cast<const short8*>(Bb + nt * 16 * 32);
            acc[0][j] = __builtin_amdgcn_mfma_f32_16x16x32_bf16(a0, bf, acc[0][j], 0, 0, 0);
            acc[1][j] = __builtin_amdgcn_mfma_f32_16x16x32_bf16(a1, bf, acc[1][j], 0, 0, 0);
        }
    }
#pragma unroll
    for (int j = 0; j < NTpW; ++j) {
        int n = (w + 4 * j) * 16 + am;
#pragma unroll
        for (int r2 = 0; r2 < 2; ++r2)
#pragma unroll
            for (int i = 0; i < 4; ++i) {
                int m = m0 + r2 * 16 + aq * 4 + i;
                part[((size_t)z * M_ + m) * NN + n] = acc[r2][j][i];
            }
    }
}

// ---------------- K5d: final gate (r-gate recomputed inline) ----------------
__global__ void k_final(const float* __restrict__ pru, const float* __restrict__ pc,
                        const float* __restrict__ h,
                        const int* __restrict__ nb, const int* __restrict__ nn,
                        float* __restrict__ out) {
    int idx = blockIdx.x * 256 + threadIdx.x;
    if (idx >= M_ * D_) return;
    int m = idx >> 6, o = idx & 63;
    const size_t Su = (size_t)M_ * 128;
    size_t br_ = (size_t)m * 128 + o;
    size_t bu = br_ + 64;
    float sr = 0.f, su = 0.f;
#pragma unroll
    for (int z = 0; z < ZS; ++z) { sr += pru[z * Su + br_]; su += pru[z * Su + bu]; }
    float rv = 1.f / (1.f + __expf(-sr));
    float uv = 1.f / (1.f + __expf(-su));
    const size_t Sc = (size_t)M_ * 64;
    size_t bcx = (size_t)m * 64 + o;
    float sc = 0.f;
#pragma unroll
    for (int z = 0; z < ZS; ++z) sc += pc[z * Sc + bcx];
    float cand = tanhf(sc);
    int b = nb[m], n = nn[m];
    float hn = rv * h[(b * N_ + n) * D_ + o];
    out[idx] = (1.f - uv) * hn + uv * cand;
}

extern "C" void kernel_launch(void* const* d_in, const int* in_sizes, int n_in,
                              void* d_out, int out_size, void* d_ws, size_t ws_size,
                              hipStream_t stream) {
    const float* x   = (const float*)d_in[0];
    const float* h   = (const float*)d_in[1];
    const float* qv  = (const float*)d_in[2];
    const int*   adj = (const int*)d_in[3];
    const int*   nb  = (const int*)d_in[4];
    const int*   nn  = (const int*)d_in[5];
    const float* Wq  = (const float*)d_in[6];
    const float* bq  = (const float*)d_in[7];
    const float* Wk  = (const float*)d_in[8];
    const float* bk  = (const float*)d_in[9];
    const float* Wv  = (const float*)d_in[10];
    const float* bv  = (const float*)d_in[11];
    const float* W1  = (const float*)d_in[12];
    const float* b1  = (const float*)d_in[13];
    const float* W2  = (const float*)d_in[14];
    const float* b2  = (const float*)d_in[15];
    const float* Wr  = (const float*)d_in[16];
    const float* br  = (const float*)d_in[17];
    const float* Wu  = (const float*)d_in[18];
    const float* bu  = (const float*)d_in[19];
    const float* Wc  = (const float*)d_in[20];
    const float* bc  = (const float*)d_in[21];
    float* ws = (float*)d_ws;
    float* out = (float*)d_out;

    ushort_t* cb   = (ushort_t*)(ws + o_cb);
    ushort_t* qb   = (ushort_t*)(ws + o_qb);
    ushort_t* kb   = (ushort_t*)(ws + o_kb);
    u64*      ab   = (u64*)(ws + o_adjb);
    ushort_t* wqk  = (ushort_t*)(ws + o_wqk);
    ushort_t* wvt  = (ushort_t*)(ws + o_wvt);
    ushort_t* vTg  = (ushort_t*)(ws + o_vT);
    ushort_t* hpb  = (ushort_t*)(ws + o_hpb);
    float* cpost = ws + o_cpost;
    ushort_t* W1T  = (ushort_t*)(ws + o_W1T);
    ushort_t* W2T  = (ushort_t*)(ws + o_W2T);
    ushort_t* wtru = (ushort_t*)(ws + o_wtru);
    ushort_t* wtc  = (ushort_t*)(ws + o_wtc);
    ushort_t* Abuf = (ushort_t*)(ws + o_A);
    float* pru   = ws + o_pru;
    float* pc    = ws + o_pc2;

    k_prep<<<(SEG6 + 255) / 256, 256, 0, stream>>>(
        x, h, Wq, bq, Wk, bk, Wv, bv, W1, W2, Wr, br, Wu, bu, Wc, bc, adj,
        cb, wqk, wvt, W1T, W2T, wtru, wtc, ab);
    k_qkv<<<dim3(NG / 16, H_), 256, 0, stream>>>(cb, wqk, wvt, qb, kb, vTg);
    k_attn<<<dim3(M_ / 16, H_), 256, 0, stream>>>(qb, kb, vTg, ab, nb, nn, hpb);
    k_mlp<<<M_ / 16, 256, 0, stream>>>(hpb, W1T, b1, W2T, b2, x, h, nb, nn, cpost);
    k_arow<<<M_, 256, 0, stream>>>(cpost, qv, Abuf);
    k_gemm<128><<<dim3(M_ / 32, ZS), 256, 0, stream>>>(Abuf, wtru, pru);
    k_arow2<<<M_, 256, 0, stream>>>(x, h, nb, nn, pru, qv, Abuf);
    k_gemm<64><<<dim3(M_ / 32, ZS), 256, 0, stream>>>(Abuf, wtc, pc);
    k_final<<<(M_ * D_ + 255) / 256, 256, 0, stream>>>(pru, pc, h, nb, nn, out);
}